// Round 1
// baseline (1353.376 us; speedup 1.0000x reference)
//
#include <hip/hip_runtime.h>
#include <stdint.h>

#pragma clang fp contract(off)

// ======================= JAX threefry2x32 reproduction =======================
// JAX >= 0.5 defaults jax_threefry_partitionable=True:
//   split(key,n)[j]      = full block tf(key, 0, j)
//   random_bits(key,32)i = o0 ^ o1 of tf(key, 0, i)
// Legacy (flag=0): iota(2n)/halves split and iota(size)/halves bits.
// If absmax ~O(1) with 1, flip to 0 next round.
#define JAX_PARTITIONABLE 1

struct KeyT { uint32_t a, b; };

__device__ __forceinline__ void tf_round(uint32_t &x0, uint32_t &x1, int r) {
  x0 += x1;
  x1 = (x1 << r) | (x1 >> (32 - r));
  x1 ^= x0;
}

__device__ KeyT tf(KeyT k, uint32_t x0, uint32_t x1) {
  uint32_t ks2 = k.a ^ k.b ^ 0x1BD11BDAu;
  x0 += k.a; x1 += k.b;
  tf_round(x0, x1, 13); tf_round(x0, x1, 15); tf_round(x0, x1, 26); tf_round(x0, x1, 6);
  x0 += k.b; x1 += ks2 + 1u;
  tf_round(x0, x1, 17); tf_round(x0, x1, 29); tf_round(x0, x1, 16); tf_round(x0, x1, 24);
  x0 += ks2; x1 += k.a + 2u;
  tf_round(x0, x1, 13); tf_round(x0, x1, 15); tf_round(x0, x1, 26); tf_round(x0, x1, 6);
  x0 += k.a; x1 += k.b + 3u;
  tf_round(x0, x1, 17); tf_round(x0, x1, 29); tf_round(x0, x1, 16); tf_round(x0, x1, 24);
  x0 += k.b; x1 += ks2 + 4u;
  tf_round(x0, x1, 13); tf_round(x0, x1, 15); tf_round(x0, x1, 26); tf_round(x0, x1, 6);
  x0 += ks2; x1 += k.a + 5u;
  KeyT o; o.a = x0; o.b = x1;
  return o;
}

// random_bits(key, 32, (size,)) element i
__device__ uint32_t rb32(KeyT key, uint32_t size, uint32_t i) {
#if JAX_PARTITIONABLE
  (void)size;
  KeyT o = tf(key, 0u, i);
  return o.a ^ o.b;
#else
  uint32_t h = (size + 1u) >> 1;           // padded half size
  if (i < h) {
    uint32_t partner = h + i;
    if (partner >= size) partner = 0u;     // odd-size zero pad
    return tf(key, i, partner).a;
  } else {
    return tf(key, i - h, i).b;
  }
#endif
}

// jax.random.split(key, n)[j]
__device__ KeyT key_split(KeyT key, uint32_t n, uint32_t j) {
#if JAX_PARTITIONABLE
  (void)n;
  return tf(key, 0u, j);
#else
  KeyT r;
  uint32_t i0 = 2u * j, i1 = 2u * j + 1u;
  r.a = (i0 < n) ? tf(key, i0, i0 + n).a : tf(key, i0 - n, i0).b;
  r.b = (i1 < n) ? tf(key, i1, i1 + n).a : tf(key, i1 - n, i1).b;
  return r;
#endif
}

// ======================= float mappings (match XLA) =======================
__device__ __forceinline__ float u01_from_bits(uint32_t bits) {
  return __uint_as_float((bits >> 9) | 0x3f800000u) - 1.0f;  // [0,1)
}

__device__ float erfinv_xla(float x) {  // XLA ErfInv32 (Giles polynomials)
  float w = -log1pf(-x * x);
  float p;
  if (w < 5.0f) {
    w = w - 2.5f;
    p = 2.81022636e-08f;
    p = 3.43273939e-07f + p * w;
    p = -3.5233877e-06f + p * w;
    p = -4.39150654e-06f + p * w;
    p = 0.00021858087f + p * w;
    p = -0.00125372503f + p * w;
    p = -0.00417768164f + p * w;
    p = 0.246640727f + p * w;
    p = 1.50140941f + p * w;
  } else {
    w = sqrtf(w) - 3.0f;
    p = -0.000200214257f;
    p = 0.000100950558f + p * w;
    p = 0.00134934322f + p * w;
    p = -0.00367342844f + p * w;
    p = 0.00573950773f + p * w;
    p = -0.0076224613f + p * w;
    p = 0.00943887047f + p * w;
    p = 1.00167406f + p * w;
    p = 2.83297682f + p * w;
  }
  return p * x;
}

__device__ float uniform01_scalar(KeyT key) {   // uniform(key, (), f32, 0, 1)
  return u01_from_bits(rb32(key, 1u, 0u));
}

__device__ float normal_scalar(KeyT key) {      // jax.random.normal scalar f32
  uint32_t bits = rb32(key, 1u, 0u);
  float f = u01_from_bits(bits);
  const float lo = -0.99999994f;                // nextafter(-1, 0) in f32
  float u = f * 2.0f + lo;                      // (hi-lo) rounds to exactly 2.0f
  u = fmaxf(lo, u);
  return 1.41421354f * erfinv_xla(u);           // float32(sqrt(2)) * erfinv
}

// jax.random.gamma _gamma_one (Marsaglia-Tsang, exact split discipline)
__device__ float gamma_one(KeyT key, float alpha) {
  KeyT sub = key_split(key, 2u, 1u);            // boost subkey
  KeyT nk  = key_split(key, 2u, 0u);
  key = nk;
  bool boost_mask = (alpha >= 1.0f);
  float alpha_eff = boost_mask ? alpha : (alpha + 1.0f);
  float d = alpha_eff - 0.33333334f;
  float c = 0.33333334f / sqrtf(d);
  float X = 0.0f, V = 1.0f, U = 2.0f;
  // reject while (U >= 1 - 0.0331 X^2) && (log U >= X/2 + d - dV + d log V)
  while ((U >= 1.0f - 0.0331f * (X * X)) &&
         (logf(U) >= 0.5f * X + d - d * V + d * logf(V))) {
    KeyT k0 = key_split(key, 3u, 0u);
    KeyT xk = key_split(key, 3u, 1u);
    KeyT Uk = key_split(key, 3u, 2u);
    key = k0;
    float x = 0.0f, v = -1.0f;
    KeyT ik = xk;
    while (v <= 0.0f) {
      KeyT ik2 = key_split(ik, 2u, 0u);
      KeyT sk  = key_split(ik, 2u, 1u);
      ik = ik2;
      x = normal_scalar(sk);
      v = 1.0f + c * x;
    }
    X = x * x;
    V = (v * v) * v;
    U = uniform01_scalar(Uk);
  }
  float s = d * V;
  if (!boost_mask) {
    s = s * powf(uniform01_scalar(sub), 1.0f / alpha);  // alpha = alpha_orig
  }
  return s;
}

// ======================= kernels =======================
#define GDIM 18000
#define NROW 1000
#define NCT  10
#define TCNT 500

// K1: alpha row0 -> gamma -> logits -> 500 categorical draws -> counts0[10].
// Also zeroes totals (= d_out) for K3's atomics.
__global__ __launch_bounds__(256) void bs_rng(const float* __restrict__ x,
                                              const float* __restrict__ W,
                                              const float* __restrict__ bias,
                                              int* __restrict__ counts,
                                              float* __restrict__ totals) {
  int tid = threadIdx.x;
  for (int g = tid; g < GDIM; g += 256) totals[g] = 0.0f;

  __shared__ float gs[NCT];
  __shared__ float lg[NCT];
  __shared__ int   cnt[NCT];
  if (tid < NCT) cnt[tid] = 0;

  KeyT root;  root.a = 0u; root.b = 42u;            // jax.random.key(42)
  KeyT k_dir = key_split(root, 2u, 0u);
  KeyT kg    = key_split(k_dir, 2u, 0u);
  KeyT kc    = key_split(k_dir, 2u, 1u);

  if (tid < NCT) {
    int k = tid;
    float acc = 0.0f;
    for (int i = 0; i < 64; ++i) acc += x[i] * W[i * NCT + k];  // x row 0
    acc += bias[k];
    float alpha = fmaxf(acc, 0.0f) + 1e-6f;         // relu + ALPHA_EPS
    KeyT gk = key_split(kg, 40u, (uint32_t)k);      // element (0,k) of (4,10)
    gs[k] = gamma_one(gk, alpha);
  }
  __syncthreads();
  if (tid == 0) {
    float s = 0.0f;
    for (int k = 0; k < NCT; ++k) s += gs[k];
    for (int k = 0; k < NCT; ++k) lg[k] = logf(gs[k] / s);
  }
  __syncthreads();

  const float tiny = 1.17549435e-38f;
  for (int t = tid; t < TCNT; t += 256) {
    float best = -__builtin_inff();
    int bi = 0;
    for (int k = 0; k < NCT; ++k) {
      uint32_t idx = (uint32_t)(t * 40 + k);        // (t, b=0, k) in (500,4,10)
      uint32_t bits = rb32(kc, 20000u, idx);
      float f = u01_from_bits(bits);
      float u = fmaxf(tiny, f + tiny);              // uniform(tiny, 1)
      float gum = -logf(-logf(u));
      float val = gum + lg[k];
      if (val > best) { best = val; bi = k; }       // argmax, first-max ties
    }
    atomicAdd(&cnt[bi], 1);
  }
  __syncthreads();
  if (tid < NCT) counts[tid] = cnt[tid];
}

// K2: per celltype, rank rows by shuffle sort-bits; rows with rank < k_c are
// the reference's perm[:k_c]. Write flat list rows[prefix_c + slot] = c*1000+n.
__global__ __launch_bounds__(256) void bs_perm(const int* __restrict__ counts,
                                               int* __restrict__ rows) {
  int c = blockIdx.x;
  int tid = threadIdx.x;
  __shared__ uint32_t sb[NROW];
  __shared__ int kc_s, pre_s, slot;
  if (tid == 0) {
    slot = 0;
    int pre = 0;
    for (int i = 0; i < c; ++i) pre += counts[i];
    pre_s = pre;
    kc_s = counts[c];
  }
  KeyT root;  root.a = 0u; root.b = 42u;
  KeyT k_sub = key_split(root, 2u, 1u);
  KeyT ck    = key_split(k_sub, (uint32_t)NCT, (uint32_t)c);
  KeyT sk    = key_split(ck, 2u, 1u);             // _shuffle: key,subkey=split
  for (int n = tid; n < NROW; n += 256) sb[n] = rb32(sk, (uint32_t)NROW, (uint32_t)n);
  __syncthreads();

  uint32_t myb[4]; int myn[4]; int rank[4];
  int m_cnt = 0;
  for (int n = tid; n < NROW; n += 256) { myn[m_cnt] = n; myb[m_cnt] = sb[n]; rank[m_cnt] = 0; ++m_cnt; }
  for (int m = 0; m < NROW; ++m) {
    uint32_t bm = sb[m];
    for (int j = 0; j < m_cnt; ++j)
      rank[j] += (bm < myb[j]) || (bm == myb[j] && m < myn[j]);  // stable sort rank
  }
  for (int j = 0; j < m_cnt; ++j) {
    if (rank[j] < kc_s) {
      int s = atomicAdd(&slot, 1);
      rows[pre_s + s] = c * NROW + myn[j];
    }
  }
}

// K3: totals[g] += sum over 25-row chunk of selected rows. grid (71, 20).
__global__ __launch_bounds__(256) void bs_sum(const float* __restrict__ sc,
                                              const int* __restrict__ rows,
                                              float* __restrict__ totals) {
  __shared__ int rloc[25];
  int tid = threadIdx.x;
  int base = blockIdx.y * 25;
  if (tid < 25) rloc[tid] = rows[base + tid];
  __syncthreads();
  int g = blockIdx.x * 256 + tid;
  if (g < GDIM) {
    float acc = 0.0f;
#pragma unroll
    for (int i = 0; i < 25; ++i) {
      long long off = (long long)rloc[i] * GDIM + g;
      acc += sc[off];
    }
    atomicAdd(&totals[g], acc);
  }
}

// K4: z=log1p(total) -> LayerNorm(global mean/var) -> min-max -> out (in place).
__global__ __launch_bounds__(1024) void bs_norm(float* __restrict__ totals,
                                                const float* __restrict__ gma,
                                                const float* __restrict__ bta,
                                                float* __restrict__ out) {
  int tid = threadIdx.x;
  __shared__ double red[1024];
  float z[18];
  int cnt = 0;
  double s = 0.0;
  for (int g = tid; g < GDIM; g += 1024) {
    float zz = log1pf(totals[g]);
    z[cnt++] = zz;
    s += (double)zz;
  }
  red[tid] = s; __syncthreads();
  for (int st = 512; st > 0; st >>= 1) { if (tid < st) red[tid] += red[tid + st]; __syncthreads(); }
  float mean = (float)(red[0] / (double)GDIM);
  __syncthreads();

  double v = 0.0;
  for (int j = 0; j < cnt; ++j) { float d = z[j] - mean; v += (double)d * (double)d; }
  red[tid] = v; __syncthreads();
  for (int st = 512; st > 0; st >>= 1) { if (tid < st) red[tid] += red[tid + st]; __syncthreads(); }
  float var = (float)(red[0] / (double)GDIM);
  __syncthreads();

  float rs = rsqrtf(var + 1e-3f);
  float mn = 3.4e38f, mx = -3.4e38f;
  for (int j = 0; j < cnt; ++j) {
    int g = tid + j * 1024;
    float zn = (z[j] - mean) * rs * gma[g] + bta[g];
    z[j] = zn;
    mn = fminf(mn, zn);
    mx = fmaxf(mx, zn);
  }
  red[tid] = (double)mn; __syncthreads();
  for (int st = 512; st > 0; st >>= 1) { if (tid < st) red[tid] = fmin(red[tid], red[tid + st]); __syncthreads(); }
  float lo = (float)red[0]; __syncthreads();
  red[tid] = (double)mx; __syncthreads();
  for (int st = 512; st > 0; st >>= 1) { if (tid < st) red[tid] = fmax(red[tid], red[tid + st]); __syncthreads(); }
  float hi = (float)red[0];
  float denom = hi - lo;
  for (int j = 0; j < cnt; ++j) {
    int g = tid + j * 1024;
    out[g] = (denom == 0.0f) ? 0.0f : (z[j] - lo) / denom;
  }
}

extern "C" void kernel_launch(void* const* d_in, const int* in_sizes, int n_in,
                              void* d_out, int out_size, void* d_ws, size_t ws_size,
                              hipStream_t stream) {
  (void)in_sizes; (void)n_in; (void)out_size; (void)ws_size;
  const float* x   = (const float*)d_in[0];   // (4,64)
  const float* W   = (const float*)d_in[1];   // (64,10)
  const float* b   = (const float*)d_in[2];   // (10,)
  const float* sc  = (const float*)d_in[3];   // (10,1000,18000)
  const float* gma = (const float*)d_in[4];   // (18000,)
  const float* bta = (const float*)d_in[5];   // (18000,)
  float* out = (float*)d_out;                 // (18000,) f32

  int* counts = (int*)d_ws;                   // 10 ints
  int* rows   = counts + 16;                  // 500 ints
  float* totals = out;                        // accumulate in d_out, K4 in-place

  hipLaunchKernelGGL(bs_rng,  dim3(1),      dim3(256),  0, stream, x, W, b, counts, totals);
  hipLaunchKernelGGL(bs_perm, dim3(10),     dim3(256),  0, stream, counts, rows);
  hipLaunchKernelGGL(bs_sum,  dim3(71, 20), dim3(256),  0, stream, sc, rows, totals);
  hipLaunchKernelGGL(bs_norm, dim3(1),      dim3(1024), 0, stream, totals, gma, bta, out);
}

// Round 2
// 895.150 us; speedup vs baseline: 1.5119x; 1.5119x over previous
//
#include <hip/hip_runtime.h>
#include <stdint.h>

#pragma clang fp contract(off)

// ======================= JAX threefry2x32 reproduction =======================
// jax_threefry_partitionable=True (verified round 1: absmax 3.9e-3 pass):
//   split(key,n)[j]      = full block tf(key, 0, j)
//   random_bits(key,32)i = o0 ^ o1 of tf(key, 0, i)
#define JAX_PARTITIONABLE 1

struct KeyT { uint32_t a, b; };

__device__ __forceinline__ void tf_round(uint32_t &x0, uint32_t &x1, int r) {
  x0 += x1;
  x1 = (x1 << r) | (x1 >> (32 - r));
  x1 ^= x0;
}

__device__ KeyT tf(KeyT k, uint32_t x0, uint32_t x1) {
  uint32_t ks2 = k.a ^ k.b ^ 0x1BD11BDAu;
  x0 += k.a; x1 += k.b;
  tf_round(x0, x1, 13); tf_round(x0, x1, 15); tf_round(x0, x1, 26); tf_round(x0, x1, 6);
  x0 += k.b; x1 += ks2 + 1u;
  tf_round(x0, x1, 17); tf_round(x0, x1, 29); tf_round(x0, x1, 16); tf_round(x0, x1, 24);
  x0 += ks2; x1 += k.a + 2u;
  tf_round(x0, x1, 13); tf_round(x0, x1, 15); tf_round(x0, x1, 26); tf_round(x0, x1, 6);
  x0 += k.a; x1 += k.b + 3u;
  tf_round(x0, x1, 17); tf_round(x0, x1, 29); tf_round(x0, x1, 16); tf_round(x0, x1, 24);
  x0 += k.b; x1 += ks2 + 4u;
  tf_round(x0, x1, 13); tf_round(x0, x1, 15); tf_round(x0, x1, 26); tf_round(x0, x1, 6);
  x0 += ks2; x1 += k.a + 5u;
  KeyT o; o.a = x0; o.b = x1;
  return o;
}

// random_bits(key, 32, (size,)) element i
__device__ uint32_t rb32(KeyT key, uint32_t size, uint32_t i) {
#if JAX_PARTITIONABLE
  (void)size;
  KeyT o = tf(key, 0u, i);
  return o.a ^ o.b;
#else
  uint32_t h = (size + 1u) >> 1;
  if (i < h) {
    uint32_t partner = h + i;
    if (partner >= size) partner = 0u;
    return tf(key, i, partner).a;
  } else {
    return tf(key, i - h, i).b;
  }
#endif
}

// jax.random.split(key, n)[j]
__device__ KeyT key_split(KeyT key, uint32_t n, uint32_t j) {
#if JAX_PARTITIONABLE
  (void)n;
  return tf(key, 0u, j);
#else
  KeyT r;
  uint32_t i0 = 2u * j, i1 = 2u * j + 1u;
  r.a = (i0 < n) ? tf(key, i0, i0 + n).a : tf(key, i0 - n, i0).b;
  r.b = (i1 < n) ? tf(key, i1, i1 + n).a : tf(key, i1 - n, i1).b;
  return r;
#endif
}

// ======================= float mappings (match XLA) =======================
__device__ __forceinline__ float u01_from_bits(uint32_t bits) {
  return __uint_as_float((bits >> 9) | 0x3f800000u) - 1.0f;  // [0,1)
}

__device__ float erfinv_xla(float x) {  // XLA ErfInv32 (Giles polynomials)
  float w = -log1pf(-x * x);
  float p;
  if (w < 5.0f) {
    w = w - 2.5f;
    p = 2.81022636e-08f;
    p = 3.43273939e-07f + p * w;
    p = -3.5233877e-06f + p * w;
    p = -4.39150654e-06f + p * w;
    p = 0.00021858087f + p * w;
    p = -0.00125372503f + p * w;
    p = -0.00417768164f + p * w;
    p = 0.246640727f + p * w;
    p = 1.50140941f + p * w;
  } else {
    w = sqrtf(w) - 3.0f;
    p = -0.000200214257f;
    p = 0.000100950558f + p * w;
    p = 0.00134934322f + p * w;
    p = -0.00367342844f + p * w;
    p = 0.00573950773f + p * w;
    p = -0.0076224613f + p * w;
    p = 0.00943887047f + p * w;
    p = 1.00167406f + p * w;
    p = 2.83297682f + p * w;
  }
  return p * x;
}

__device__ float uniform01_scalar(KeyT key) {
  return u01_from_bits(rb32(key, 1u, 0u));
}

__device__ float normal_scalar(KeyT key) {
  uint32_t bits = rb32(key, 1u, 0u);
  float f = u01_from_bits(bits);
  const float lo = -0.99999994f;                // nextafter(-1, 0) in f32
  float u = f * 2.0f + lo;
  u = fmaxf(lo, u);
  return 1.41421354f * erfinv_xla(u);
}

// jax.random.gamma _gamma_one (Marsaglia-Tsang, exact split discipline)
__device__ float gamma_one(KeyT key, float alpha) {
  KeyT sub = key_split(key, 2u, 1u);
  KeyT nk  = key_split(key, 2u, 0u);
  key = nk;
  bool boost_mask = (alpha >= 1.0f);
  float alpha_eff = boost_mask ? alpha : (alpha + 1.0f);
  float d = alpha_eff - 0.33333334f;
  float c = 0.33333334f / sqrtf(d);
  float X = 0.0f, V = 1.0f, U = 2.0f;
  while ((U >= 1.0f - 0.0331f * (X * X)) &&
         (logf(U) >= 0.5f * X + d - d * V + d * logf(V))) {
    KeyT k0 = key_split(key, 3u, 0u);
    KeyT xk = key_split(key, 3u, 1u);
    KeyT Uk = key_split(key, 3u, 2u);
    key = k0;
    float x = 0.0f, v = -1.0f;
    KeyT ik = xk;
    while (v <= 0.0f) {
      KeyT ik2 = key_split(ik, 2u, 0u);
      KeyT sk  = key_split(ik, 2u, 1u);
      ik = ik2;
      x = normal_scalar(sk);
      v = 1.0f + c * x;
    }
    X = x * x;
    V = (v * v) * v;
    U = uniform01_scalar(Uk);
  }
  float s = d * V;
  if (!boost_mask) {
    s = s * powf(uniform01_scalar(sub), 1.0f / alpha);
  }
  return s;
}

// ======================= kernels =======================
#define GDIM 18000
#define NROW 1000
#define NCT  10
#define TCNT 500

// K1: alpha row0 -> gamma -> logits -> 500 categorical draws -> counts0[10].
// Also zeroes totals (= d_out) for K3's atomics.
__global__ __launch_bounds__(256) void bs_rng(const float* __restrict__ x,
                                              const float* __restrict__ W,
                                              const float* __restrict__ bias,
                                              int* __restrict__ counts,
                                              float* __restrict__ totals) {
  int tid = threadIdx.x;
  for (int g = tid; g < GDIM; g += 256) totals[g] = 0.0f;

  __shared__ float gs[NCT];
  __shared__ float lg[NCT];
  __shared__ int   cnt[NCT];
  if (tid < NCT) cnt[tid] = 0;

  KeyT root;  root.a = 0u; root.b = 42u;            // jax.random.key(42)
  KeyT k_dir = key_split(root, 2u, 0u);
  KeyT kg    = key_split(k_dir, 2u, 0u);
  KeyT kc    = key_split(k_dir, 2u, 1u);

  if (tid < NCT) {
    int k = tid;
    float acc = 0.0f;
    for (int i = 0; i < 64; ++i) acc += x[i] * W[i * NCT + k];  // x row 0
    acc += bias[k];
    float alpha = fmaxf(acc, 0.0f) + 1e-6f;         // relu + ALPHA_EPS
    KeyT gk = key_split(kg, 40u, (uint32_t)k);      // element (0,k) of (4,10)
    gs[k] = gamma_one(gk, alpha);
  }
  __syncthreads();
  if (tid == 0) {
    float s = 0.0f;
    for (int k = 0; k < NCT; ++k) s += gs[k];
    for (int k = 0; k < NCT; ++k) lg[k] = logf(gs[k] / s);
  }
  __syncthreads();

  const float tiny = 1.17549435e-38f;
  for (int t = tid; t < TCNT; t += 256) {
    float best = -__builtin_inff();
    int bi = 0;
#pragma unroll
    for (int k = 0; k < NCT; ++k) {
      uint32_t idx = (uint32_t)(t * 40 + k);        // (t, b=0, k) in (500,4,10)
      uint32_t bits = rb32(kc, 20000u, idx);
      float f = u01_from_bits(bits);
      float u = fmaxf(tiny, f + tiny);              // uniform(tiny, 1)
      float gum = -logf(-logf(u));
      float val = gum + lg[k];
      if (val > best) { best = val; bi = k; }       // argmax, first-max ties
    }
    atomicAdd(&cnt[bi], 1);
  }
  __syncthreads();
  if (tid < NCT) counts[tid] = cnt[tid];
}

// K2: per celltype, rank rows by shuffle sort-bits; rows with rank < k_c are
// the reference's perm[:k_c]. All per-thread state in named scalars so it
// stays in VGPRs (round-1 version used dynamically-indexed arrays -> scratch
// spill -> 545 us of memory stalls at 0.95% VALUBusy).
__global__ __launch_bounds__(256) void bs_perm(const int* __restrict__ counts,
                                               int* __restrict__ rows) {
  int c = blockIdx.x;
  int tid = threadIdx.x;
  __shared__ uint32_t sb[NROW];     // 1000 * 4B, 16B-aligned, 1000 % 4 == 0
  __shared__ int kc_s, pre_s, slot;
  if (tid == 0) {
    slot = 0;
    int pre = 0;
    for (int i = 0; i < c; ++i) pre += counts[i];
    pre_s = pre;
    kc_s = counts[c];
  }
  KeyT root;  root.a = 0u; root.b = 42u;
  KeyT k_sub = key_split(root, 2u, 1u);
  KeyT ck    = key_split(k_sub, (uint32_t)NCT, (uint32_t)c);
  KeyT sk    = key_split(ck, 2u, 1u);             // _shuffle: key,subkey=split
  for (int n = tid; n < NROW; n += 256) sb[n] = rb32(sk, (uint32_t)NROW, (uint32_t)n);
  __syncthreads();

  // Rows owned by this thread (static names -> registers).
  const int n0 = tid, n1 = tid + 256, n2 = tid + 512, n3 = tid + 768;
  const bool has3 = (n3 < NROW);                  // tid < 232
  uint32_t b0 = sb[n0], b1 = sb[n1], b2 = sb[n2];
  uint32_t b3 = has3 ? sb[n3] : 0u;
  int r0 = 0, r1 = 0, r2 = 0, r3 = 0;

  const uint4* sb4 = (const uint4*)sb;
#pragma unroll 5
  for (int q = 0; q < NROW / 4; ++q) {
    uint4 v = sb4[q];                              // broadcast ds_read_b128
    int m = q * 4;
#define RANK_STEP(BM, MM)                                              \
    r0 += (BM < b0) || (BM == b0 && (MM) < n0);                        \
    r1 += (BM < b1) || (BM == b1 && (MM) < n1);                        \
    r2 += (BM < b2) || (BM == b2 && (MM) < n2);                        \
    r3 += (BM < b3) || (BM == b3 && (MM) < n3);
    RANK_STEP(v.x, m)
    RANK_STEP(v.y, m + 1)
    RANK_STEP(v.z, m + 2)
    RANK_STEP(v.w, m + 3)
#undef RANK_STEP
  }

  int kc = kc_s, pre = pre_s;
  if (r0 < kc)          rows[pre + atomicAdd(&slot, 1)] = c * NROW + n0;
  if (r1 < kc)          rows[pre + atomicAdd(&slot, 1)] = c * NROW + n1;
  if (r2 < kc)          rows[pre + atomicAdd(&slot, 1)] = c * NROW + n2;
  if (has3 && r3 < kc)  rows[pre + atomicAdd(&slot, 1)] = c * NROW + n3;
}

// K3: totals[g] += sum over 25-row chunk of selected rows. grid (71, 20).
__global__ __launch_bounds__(256) void bs_sum(const float* __restrict__ sc,
                                              const int* __restrict__ rows,
                                              float* __restrict__ totals) {
  __shared__ int rloc[25];
  int tid = threadIdx.x;
  int base = blockIdx.y * 25;
  if (tid < 25) rloc[tid] = rows[base + tid];
  __syncthreads();
  int g = blockIdx.x * 256 + tid;
  if (g < GDIM) {
    float acc = 0.0f;
#pragma unroll
    for (int i = 0; i < 25; ++i) {
      long long off = (long long)rloc[i] * GDIM + g;
      acc += sc[off];
    }
    atomicAdd(&totals[g], acc);
  }
}

// K4: z=log1p(total) -> LayerNorm(global mean/var) -> min-max -> out.
// z[] indexed only by compile-time constants (static unroll + guards) so it
// stays in VGPRs.
#define NPT 18  // ceil(18000/1024)
__global__ __launch_bounds__(1024) void bs_norm(float* __restrict__ totals,
                                                const float* __restrict__ gma,
                                                const float* __restrict__ bta,
                                                float* __restrict__ out) {
  int tid = threadIdx.x;
  __shared__ double red[1024];
  float z[NPT];
  double s = 0.0;
#pragma unroll
  for (int j = 0; j < NPT; ++j) {
    int g = tid + j * 1024;
    float zz = (g < GDIM) ? log1pf(totals[g]) : 0.0f;
    z[j] = zz;
    s += (double)zz;
  }
  red[tid] = s; __syncthreads();
  for (int st = 512; st > 0; st >>= 1) { if (tid < st) red[tid] += red[tid + st]; __syncthreads(); }
  float mean = (float)(red[0] / (double)GDIM);
  __syncthreads();

  double v = 0.0;
#pragma unroll
  for (int j = 0; j < NPT; ++j) {
    int g = tid + j * 1024;
    if (g < GDIM) { float d = z[j] - mean; v += (double)d * (double)d; }
  }
  red[tid] = v; __syncthreads();
  for (int st = 512; st > 0; st >>= 1) { if (tid < st) red[tid] += red[tid + st]; __syncthreads(); }
  float var = (float)(red[0] / (double)GDIM);
  __syncthreads();

  float rs = rsqrtf(var + 1e-3f);
  float mn = 3.4e38f, mx = -3.4e38f;
#pragma unroll
  for (int j = 0; j < NPT; ++j) {
    int g = tid + j * 1024;
    if (g < GDIM) {
      float zn = (z[j] - mean) * rs * gma[g] + bta[g];
      z[j] = zn;
      mn = fminf(mn, zn);
      mx = fmaxf(mx, zn);
    }
  }
  red[tid] = (double)mn; __syncthreads();
  for (int st = 512; st > 0; st >>= 1) { if (tid < st) red[tid] = fmin(red[tid], red[tid + st]); __syncthreads(); }
  float lo = (float)red[0]; __syncthreads();
  red[tid] = (double)mx; __syncthreads();
  for (int st = 512; st > 0; st >>= 1) { if (tid < st) red[tid] = fmax(red[tid], red[tid + st]); __syncthreads(); }
  float hi = (float)red[0];
  float denom = hi - lo;
#pragma unroll
  for (int j = 0; j < NPT; ++j) {
    int g = tid + j * 1024;
    if (g < GDIM) out[g] = (denom == 0.0f) ? 0.0f : (z[j] - lo) / denom;
  }
}

extern "C" void kernel_launch(void* const* d_in, const int* in_sizes, int n_in,
                              void* d_out, int out_size, void* d_ws, size_t ws_size,
                              hipStream_t stream) {
  (void)in_sizes; (void)n_in; (void)out_size; (void)ws_size;
  const float* x   = (const float*)d_in[0];   // (4,64)
  const float* W   = (const float*)d_in[1];   // (64,10)
  const float* b   = (const float*)d_in[2];   // (10,)
  const float* sc  = (const float*)d_in[3];   // (10,1000,18000)
  const float* gma = (const float*)d_in[4];   // (18000,)
  const float* bta = (const float*)d_in[5];   // (18000,)
  float* out = (float*)d_out;                 // (18000,) f32

  int* counts = (int*)d_ws;                   // 10 ints
  int* rows   = counts + 16;                  // 500 ints
  float* totals = out;                        // accumulate in d_out, K4 in-place

  hipLaunchKernelGGL(bs_rng,  dim3(1),      dim3(256),  0, stream, x, W, b, counts, totals);
  hipLaunchKernelGGL(bs_perm, dim3(10),     dim3(256),  0, stream, counts, rows);
  hipLaunchKernelGGL(bs_sum,  dim3(71, 20), dim3(256),  0, stream, sc, rows, totals);
  hipLaunchKernelGGL(bs_norm, dim3(1),      dim3(1024), 0, stream, totals, gma, bta, out);
}

// Round 3
// 835.252 us; speedup vs baseline: 1.6203x; 1.0717x over previous
//
#include <hip/hip_runtime.h>
#include <stdint.h>

#pragma clang fp contract(off)

// ======================= JAX threefry2x32 reproduction =======================
// jax_threefry_partitionable=True (verified round 1: absmax 3.9e-3 pass):
//   split(key,n)[j]      = full block tf(key, 0, j)
//   random_bits(key,32)i = o0 ^ o1 of tf(key, 0, i)
#define JAX_PARTITIONABLE 1

struct KeyT { uint32_t a, b; };

__device__ __forceinline__ void tf_round(uint32_t &x0, uint32_t &x1, int r) {
  x0 += x1;
  x1 = (x1 << r) | (x1 >> (32 - r));
  x1 ^= x0;
}

__device__ KeyT tf(KeyT k, uint32_t x0, uint32_t x1) {
  uint32_t ks2 = k.a ^ k.b ^ 0x1BD11BDAu;
  x0 += k.a; x1 += k.b;
  tf_round(x0, x1, 13); tf_round(x0, x1, 15); tf_round(x0, x1, 26); tf_round(x0, x1, 6);
  x0 += k.b; x1 += ks2 + 1u;
  tf_round(x0, x1, 17); tf_round(x0, x1, 29); tf_round(x0, x1, 16); tf_round(x0, x1, 24);
  x0 += ks2; x1 += k.a + 2u;
  tf_round(x0, x1, 13); tf_round(x0, x1, 15); tf_round(x0, x1, 26); tf_round(x0, x1, 6);
  x0 += k.a; x1 += k.b + 3u;
  tf_round(x0, x1, 17); tf_round(x0, x1, 29); tf_round(x0, x1, 16); tf_round(x0, x1, 24);
  x0 += k.b; x1 += ks2 + 4u;
  tf_round(x0, x1, 13); tf_round(x0, x1, 15); tf_round(x0, x1, 26); tf_round(x0, x1, 6);
  x0 += ks2; x1 += k.a + 5u;
  KeyT o; o.a = x0; o.b = x1;
  return o;
}

__device__ uint32_t rb32(KeyT key, uint32_t size, uint32_t i) {
#if JAX_PARTITIONABLE
  (void)size;
  KeyT o = tf(key, 0u, i);
  return o.a ^ o.b;
#else
  uint32_t h = (size + 1u) >> 1;
  if (i < h) {
    uint32_t partner = h + i;
    if (partner >= size) partner = 0u;
    return tf(key, i, partner).a;
  } else {
    return tf(key, i - h, i).b;
  }
#endif
}

__device__ KeyT key_split(KeyT key, uint32_t n, uint32_t j) {
#if JAX_PARTITIONABLE
  (void)n;
  return tf(key, 0u, j);
#else
  KeyT r;
  uint32_t i0 = 2u * j, i1 = 2u * j + 1u;
  r.a = (i0 < n) ? tf(key, i0, i0 + n).a : tf(key, i0 - n, i0).b;
  r.b = (i1 < n) ? tf(key, i1, i1 + n).a : tf(key, i1 - n, i1).b;
  return r;
#endif
}

// ======================= float mappings (match XLA) =======================
__device__ __forceinline__ float u01_from_bits(uint32_t bits) {
  return __uint_as_float((bits >> 9) | 0x3f800000u) - 1.0f;  // [0,1)
}

__device__ float erfinv_xla(float x) {  // XLA ErfInv32 (Giles polynomials)
  float w = -log1pf(-x * x);
  float p;
  if (w < 5.0f) {
    w = w - 2.5f;
    p = 2.81022636e-08f;
    p = 3.43273939e-07f + p * w;
    p = -3.5233877e-06f + p * w;
    p = -4.39150654e-06f + p * w;
    p = 0.00021858087f + p * w;
    p = -0.00125372503f + p * w;
    p = -0.00417768164f + p * w;
    p = 0.246640727f + p * w;
    p = 1.50140941f + p * w;
  } else {
    w = sqrtf(w) - 3.0f;
    p = -0.000200214257f;
    p = 0.000100950558f + p * w;
    p = 0.00134934322f + p * w;
    p = -0.00367342844f + p * w;
    p = 0.00573950773f + p * w;
    p = -0.0076224613f + p * w;
    p = 0.00943887047f + p * w;
    p = 1.00167406f + p * w;
    p = 2.83297682f + p * w;
  }
  return p * x;
}

__device__ float uniform01_scalar(KeyT key) {
  return u01_from_bits(rb32(key, 1u, 0u));
}

__device__ float normal_scalar(KeyT key) {
  uint32_t bits = rb32(key, 1u, 0u);
  float f = u01_from_bits(bits);
  const float lo = -0.99999994f;                // nextafter(-1, 0) in f32
  float u = f * 2.0f + lo;
  u = fmaxf(lo, u);
  return 1.41421354f * erfinv_xla(u);
}

// jax.random.gamma _gamma_one (Marsaglia-Tsang, exact split discipline)
__device__ float gamma_one(KeyT key, float alpha) {
  KeyT sub = key_split(key, 2u, 1u);
  KeyT nk  = key_split(key, 2u, 0u);
  key = nk;
  bool boost_mask = (alpha >= 1.0f);
  float alpha_eff = boost_mask ? alpha : (alpha + 1.0f);
  float d = alpha_eff - 0.33333334f;
  float c = 0.33333334f / sqrtf(d);
  float X = 0.0f, V = 1.0f, U = 2.0f;
  while ((U >= 1.0f - 0.0331f * (X * X)) &&
         (logf(U) >= 0.5f * X + d - d * V + d * logf(V))) {
    KeyT k0 = key_split(key, 3u, 0u);
    KeyT xk = key_split(key, 3u, 1u);
    KeyT Uk = key_split(key, 3u, 2u);
    key = k0;
    float x = 0.0f, v = -1.0f;
    KeyT ik = xk;
    while (v <= 0.0f) {
      KeyT ik2 = key_split(ik, 2u, 0u);
      KeyT sk  = key_split(ik, 2u, 1u);
      ik = ik2;
      x = normal_scalar(sk);
      v = 1.0f + c * x;
    }
    X = x * x;
    V = (v * v) * v;
    U = uniform01_scalar(Uk);
  }
  float s = d * V;
  if (!boost_mask) {
    s = s * powf(uniform01_scalar(sub), 1.0f / alpha);
  }
  return s;
}

// ======================= kernels =======================
#define GDIM 18000
#define NROW 1000
#define NCT  10
#define TCNT 500

// K1: alpha row0 -> gamma -> logits -> 500 categorical draws -> counts0[10].
// Also zeroes totals (= d_out) and the per-celltype slot counters.
__global__ __launch_bounds__(256) void bs_rng(const float* __restrict__ x,
                                              const float* __restrict__ W,
                                              const float* __restrict__ bias,
                                              int* __restrict__ counts,
                                              int* __restrict__ slots,
                                              float* __restrict__ totals) {
  int tid = threadIdx.x;
  for (int g = tid; g < GDIM; g += 256) totals[g] = 0.0f;
  if (tid < NCT) slots[tid] = 0;

  __shared__ float gs[NCT];
  __shared__ float lg[NCT];
  __shared__ int   cnt[NCT];
  if (tid < NCT) cnt[tid] = 0;

  KeyT root;  root.a = 0u; root.b = 42u;            // jax.random.key(42)
  KeyT k_dir = key_split(root, 2u, 0u);
  KeyT kg    = key_split(k_dir, 2u, 0u);
  KeyT kc    = key_split(k_dir, 2u, 1u);

  if (tid < NCT) {
    int k = tid;
    float acc = 0.0f;
    for (int i = 0; i < 64; ++i) acc += x[i] * W[i * NCT + k];  // x row 0
    acc += bias[k];
    float alpha = fmaxf(acc, 0.0f) + 1e-6f;         // relu + ALPHA_EPS
    KeyT gk = key_split(kg, 40u, (uint32_t)k);      // element (0,k) of (4,10)
    gs[k] = gamma_one(gk, alpha);
  }
  __syncthreads();
  if (tid == 0) {
    float s = 0.0f;
    for (int k = 0; k < NCT; ++k) s += gs[k];
    for (int k = 0; k < NCT; ++k) lg[k] = logf(gs[k] / s);
  }
  __syncthreads();

  const float tiny = 1.17549435e-38f;
  for (int t = tid; t < TCNT; t += 256) {
    float best = -__builtin_inff();
    int bi = 0;
#pragma unroll
    for (int k = 0; k < NCT; ++k) {
      uint32_t idx = (uint32_t)(t * 40 + k);        // (t, b=0, k) in (500,4,10)
      uint32_t bits = rb32(kc, 20000u, idx);
      float f = u01_from_bits(bits);
      float u = fmaxf(tiny, f + tiny);              // uniform(tiny, 1)
      float gum = -logf(-logf(u));
      float val = gum + lg[k];
      if (val > best) { best = val; bi = k; }       // argmax, first-max ties
    }
    atomicAdd(&cnt[bi], 1);
  }
  __syncthreads();
  if (tid < NCT) counts[tid] = cnt[tid];
}

// K2: rank rows by shuffle sort-bits; rows with rank < k_c are perm[:k_c].
// grid (4, 10): blockIdx.y = celltype, blockIdx.x = quarter of the rows.
// 1 row/thread (round-2 had 4 rows/thread on 10 blocks -> 4x the VALU depth).
// Slot order within a celltype's list is atomic-nondeterministic; the consumer
// only sums, so fp-reorder noise ~1e-6 << threshold.
__global__ __launch_bounds__(256) void bs_perm(const int* __restrict__ counts,
                                               int* __restrict__ slots,
                                               int* __restrict__ rows) {
  int c = blockIdx.y;
  int tid = threadIdx.x;
  __shared__ uint32_t sb[NROW];     // 16B-aligned, 1000 % 4 == 0
  __shared__ int kc_s, pre_s;
  if (tid == 0) {
    int pre = 0;
    for (int i = 0; i < c; ++i) pre += counts[i];
    pre_s = pre;
    kc_s = counts[c];
  }
  KeyT root;  root.a = 0u; root.b = 42u;
  KeyT k_sub = key_split(root, 2u, 1u);
  KeyT ck    = key_split(k_sub, (uint32_t)NCT, (uint32_t)c);
  KeyT sk    = key_split(ck, 2u, 1u);             // _shuffle: key,subkey=split
  for (int n = tid; n < NROW; n += 256) sb[n] = rb32(sk, (uint32_t)NROW, (uint32_t)n);
  __syncthreads();

  const int  n0  = blockIdx.x * 250 + tid;        // this thread's row
  const bool act = (tid < 250);
  uint32_t b0 = act ? sb[n0] : 0u;
  int r0 = 0;
  const uint4* sb4 = (const uint4*)sb;
#pragma unroll 5
  for (int q = 0; q < NROW / 4; ++q) {
    uint4 v = sb4[q];                              // broadcast ds_read_b128
    int m = q * 4;
    r0 += (v.x < b0) || (v.x == b0 && m     < n0); // stable sort rank
    r0 += (v.y < b0) || (v.y == b0 && m + 1 < n0);
    r0 += (v.z < b0) || (v.z == b0 && m + 2 < n0);
    r0 += (v.w < b0) || (v.w == b0 && m + 3 < n0);
  }
  if (act && r0 < kc_s) {
    int s = atomicAdd(&slots[c], 1);               // device-scope
    rows[pre_s + s] = c * NROW + n0;
  }
}

// K3: totals[4e..4e+3] += sum over 25-row chunk, float4 loads. grid (18, 20).
__global__ __launch_bounds__(256) void bs_sum(const float* __restrict__ sc,
                                              const int* __restrict__ rows,
                                              float* __restrict__ totals) {
  __shared__ int rloc[25];
  int tid = threadIdx.x;
  int base = blockIdx.y * 25;
  if (tid < 25) rloc[tid] = rows[base + tid];
  __syncthreads();
  int e4 = blockIdx.x * 256 + tid;                 // float4 index
  if (e4 < GDIM / 4) {
    int g = e4 * 4;
    float ax = 0.0f, ay = 0.0f, az = 0.0f, aw = 0.0f;
#pragma unroll
    for (int i = 0; i < 25; ++i) {
      const float4 v = *(const float4*)(sc + (size_t)rloc[i] * GDIM + g);
      ax += v.x; ay += v.y; az += v.z; aw += v.w;
    }
    atomicAdd(&totals[g],     ax);
    atomicAdd(&totals[g + 1], ay);
    atomicAdd(&totals[g + 2], az);
    atomicAdd(&totals[g + 3], aw);
  }
}

// ---- block reductions via wave shuffles (1024 threads = 16 waves) ----
__device__ __forceinline__ double wred_add(double v) {
#pragma unroll
  for (int o = 32; o > 0; o >>= 1) v += __shfl_down(v, o, 64);
  return v;
}
__device__ __forceinline__ float wred_min(float v) {
#pragma unroll
  for (int o = 32; o > 0; o >>= 1) v = fminf(v, __shfl_down(v, o, 64));
  return v;
}
__device__ __forceinline__ float wred_max(float v) {
#pragma unroll
  for (int o = 32; o > 0; o >>= 1) v = fmaxf(v, __shfl_down(v, o, 64));
  return v;
}

__device__ double block_add(double v, double* wbuf, int tid) {
  int lane = tid & 63, wid = tid >> 6;
  double t = wred_add(v);
  __syncthreads();                                  // protect wbuf reuse
  if (lane == 0) wbuf[wid] = t;
  __syncthreads();
  if (wid == 0) {
    double x = (lane < 16) ? wbuf[lane] : 0.0;
    x = wred_add(x);
    if (lane == 0) wbuf[16] = x;
  }
  __syncthreads();
  return wbuf[16];
}
__device__ float block_min(float v, double* wbuf, int tid) {
  int lane = tid & 63, wid = tid >> 6;
  float t = wred_min(v);
  __syncthreads();
  if (lane == 0) wbuf[wid] = (double)t;
  __syncthreads();
  if (wid == 0) {
    float x = (lane < 16) ? (float)wbuf[lane] : 3.4e38f;
    x = wred_min(x);
    if (lane == 0) wbuf[16] = (double)x;
  }
  __syncthreads();
  return (float)wbuf[16];
}
__device__ float block_max(float v, double* wbuf, int tid) {
  int lane = tid & 63, wid = tid >> 6;
  float t = wred_max(v);
  __syncthreads();
  if (lane == 0) wbuf[wid] = (double)t;
  __syncthreads();
  if (wid == 0) {
    float x = (lane < 16) ? (float)wbuf[lane] : -3.4e38f;
    x = wred_max(x);
    if (lane == 0) wbuf[16] = (double)x;
  }
  __syncthreads();
  return (float)wbuf[16];
}

// K4: z=log1p(total) -> LayerNorm(global mean/var) -> min-max -> out.
#define NPT 18  // ceil(18000/1024)
__global__ __launch_bounds__(1024) void bs_norm(float* __restrict__ totals,
                                                const float* __restrict__ gma,
                                                const float* __restrict__ bta,
                                                float* __restrict__ out) {
  int tid = threadIdx.x;
  __shared__ double wbuf[17];
  float z[NPT];
  double s = 0.0;
#pragma unroll
  for (int j = 0; j < NPT; ++j) {
    int g = tid + j * 1024;
    float zz = (g < GDIM) ? log1pf(totals[g]) : 0.0f;
    z[j] = zz;
    s += (double)zz;
  }
  float mean = (float)(block_add(s, wbuf, tid) / (double)GDIM);

  double v = 0.0;
#pragma unroll
  for (int j = 0; j < NPT; ++j) {
    int g = tid + j * 1024;
    if (g < GDIM) { float d = z[j] - mean; v += (double)d * (double)d; }
  }
  float var = (float)(block_add(v, wbuf, tid) / (double)GDIM);

  float rs = rsqrtf(var + 1e-3f);
  float mn = 3.4e38f, mx = -3.4e38f;
#pragma unroll
  for (int j = 0; j < NPT; ++j) {
    int g = tid + j * 1024;
    if (g < GDIM) {
      float zn = (z[j] - mean) * rs * gma[g] + bta[g];
      z[j] = zn;
      mn = fminf(mn, zn);
      mx = fmaxf(mx, zn);
    }
  }
  float lo = block_min(mn, wbuf, tid);
  float hi = block_max(mx, wbuf, tid);
  float denom = hi - lo;
#pragma unroll
  for (int j = 0; j < NPT; ++j) {
    int g = tid + j * 1024;
    if (g < GDIM) out[g] = (denom == 0.0f) ? 0.0f : (z[j] - lo) / denom;
  }
}

extern "C" void kernel_launch(void* const* d_in, const int* in_sizes, int n_in,
                              void* d_out, int out_size, void* d_ws, size_t ws_size,
                              hipStream_t stream) {
  (void)in_sizes; (void)n_in; (void)out_size; (void)ws_size;
  const float* x   = (const float*)d_in[0];   // (4,64)
  const float* W   = (const float*)d_in[1];   // (64,10)
  const float* b   = (const float*)d_in[2];   // (10,)
  const float* sc  = (const float*)d_in[3];   // (10,1000,18000)
  const float* gma = (const float*)d_in[4];   // (18000,)
  const float* bta = (const float*)d_in[5];   // (18000,)
  float* out = (float*)d_out;                 // (18000,) f32

  int* counts = (int*)d_ws;                   // 10 ints
  int* slots  = counts + 16;                  // 10 ints (per-celltype cursors)
  int* rows   = counts + 32;                  // 500 ints
  float* totals = out;                        // accumulate in d_out, K4 in-place

  hipLaunchKernelGGL(bs_rng,  dim3(1),      dim3(256),  0, stream, x, W, b, counts, slots, totals);
  hipLaunchKernelGGL(bs_perm, dim3(4, 10),  dim3(256),  0, stream, counts, slots, rows);
  hipLaunchKernelGGL(bs_sum,  dim3(18, 20), dim3(256),  0, stream, sc, rows, totals);
  hipLaunchKernelGGL(bs_norm, dim3(1),      dim3(1024), 0, stream, totals, gma, bta, out);
}